// Round 4
// baseline (278.801 us; speedup 1.0000x reference)
//
#include <hip/hip_runtime.h>

#define B_ 4
#define N_ 4096
#define D_ 64

typedef __bf16 bf16_t;
typedef bf16_t bf16x8 __attribute__((ext_vector_type(8)));
typedef float f32x16 __attribute__((ext_vector_type(16)));

// exp2 via v_exp_f32 (inputs are pre-scaled into log2 domain)
#if __has_builtin(__builtin_amdgcn_exp2f)
#define EXP2F __builtin_amdgcn_exp2f
#else
#define EXP2F exp2f
#endif

// sqrt(log2(e)): scaling both MFMA operands by this puts S directly in
// log2 domain, so the softmax epilogue is sub+exp2 (no per-element mul).
#define SQRT_LOG2E 1.2011224087864498f

// Kernel 1: fp32 -> bf16 (scaled) + per-row norms + PACK into MFMA fragment
// order. Packed layout: P[g][i][lane][j] = X[g*32 + (lane&31)]
// [(lane>>5)*8 + i*16 + j]  -- the exact order a wave's lanes consume
// fragment i of row-group g. A wave-load of one fragment is a contiguous 1 KB.
__global__ void conv_pack_kernel(const float* __restrict__ X,
                                 bf16_t* __restrict__ Xp,
                                 float* __restrict__ norms) {
    const int g    = blockIdx.x * 4 + (threadIdx.x >> 6); // row-group (32 rows)
    const int lane = threadIdx.x & 63;
    const int mcol = lane & 31;
    const int half = lane >> 5;
    const int row  = g * 32 + mcol;                       // global row in [0, B*N)

    const float* xr = X + (size_t)row * D_ + half * 8;
    float sq = 0.0f;
    #pragma unroll
    for (int i = 0; i < 4; ++i) {
        float4 u0 = *(const float4*)(xr + i * 16);
        float4 u1 = *(const float4*)(xr + i * 16 + 4);
        float v[8] = {u0.x, u0.y, u0.z, u0.w, u1.x, u1.y, u1.z, u1.w};
        bf16x8 f;
        #pragma unroll
        for (int j = 0; j < 8; ++j) {
            float x = v[j] * SQRT_LOG2E;
            sq += x * x;
            f[j] = (bf16_t)x;
        }
        *(bf16x8*)(Xp + ((size_t)(g * 4 + i) * 64 + lane) * 8) = f;
    }
    sq += __shfl_xor(sq, 32);   // combine the two k-halves of the row
    if (half == 0) norms[row] = sq;
}

// Kernel 2: each block owns 64 rows (TWO packed row-groups) of one batch;
// 8 waves, each wave owns a 32-col strip of a 256-col tile. Every B-fragment
// load now feeds 8 MFMAs (two row-groups) instead of 4 -- halves load issue
// and L2 panel traffic. Grid = 256 blocks (1/CU, 2 waves/SIMD; R1 showed
// occupancy-insensitivity). launch_bounds(512,2) -> 256-VGPR budget, no spill.
__global__ __launch_bounds__(512, 2) void softmax_xxt_kernel(
        const bf16_t* __restrict__ Xp,
        const float* __restrict__ norms,
        float* __restrict__ Out) {
    const int tid  = threadIdx.x;
    const int wave = tid >> 6;                 // 0..7
    const int lane = tid & 63;
    const int b    = blockIdx.x >> 6;          // 64 row-strips per batch
    const int gb   = blockIdx.x & 63;          // 64-row strip within batch
    const int rowbase = gb * 64;

    const bf16_t* Pb = Xp + (size_t)b * N_ * D_;   // packed panel for batch
    const int mcol = lane & 31;
    const int half = lane >> 5;

    // A fragments for the two row-groups (packed groups 2*gb, 2*gb+1)
    const bf16_t* ap = Pb + (size_t)(gb * 2) * 2048 + (size_t)lane * 8;
    bf16x8 a[2][4];
    #pragma unroll
    for (int gi = 0; gi < 2; ++gi)
        #pragma unroll
        for (int k = 0; k < 4; ++k)
            a[gi][k] = *(const bf16x8*)(ap + (size_t)gi * 2048 + k * 512);

    // Stabilizer m2 (log2 domain) for the 16 rows each lane's acc regs map to:
    // row_local = (reg&3) + 8*(reg>>2) + 4*(lane>>5)   [measured m74/m101]
    float lse[2][16];
    {
        const float* nb = norms + b * N_ + rowbase;
        #pragma unroll
        for (int gi = 0; gi < 2; ++gi)
            #pragma unroll
            for (int r = 0; r < 16; ++r) {
                int rl = (r & 3) + 8 * (r >> 2) + 4 * half;
                lse[gi][r] = nb[gi * 32 + rl];
            }
    }

    __shared__ float partials[8][64];

    // ---------------- pass 1: denominators ----------------
    float sums[2][16];
    #pragma unroll
    for (int gi = 0; gi < 2; ++gi)
        #pragma unroll
        for (int r = 0; r < 16; ++r) sums[gi][r] = 0.0f;

    {
        const bf16_t* bp0 = Pb + (size_t)wave * 2048 + (size_t)lane * 8;
        bf16x8 nb0 = *(const bf16x8*)(bp0);
        bf16x8 nb1 = *(const bf16x8*)(bp0 + 512);
        bf16x8 nb2 = *(const bf16x8*)(bp0 + 1024);
        bf16x8 nb3 = *(const bf16x8*)(bp0 + 1536);
        for (int t = 0; t < N_ / 256; ++t) {
            bf16x8 b0 = nb0, b1 = nb1, b2 = nb2, b3 = nb3;
            if (t + 1 < N_ / 256) {
                const bf16_t* np = Pb + (size_t)((t + 1) * 8 + wave) * 2048
                                      + (size_t)lane * 8;
                nb0 = *(const bf16x8*)(np);
                nb1 = *(const bf16x8*)(np + 512);
                nb2 = *(const bf16x8*)(np + 1024);
                nb3 = *(const bf16x8*)(np + 1536);
            }
            #pragma unroll
            for (int gi = 0; gi < 2; ++gi) {
                f32x16 acc;
                #pragma unroll
                for (int i = 0; i < 16; ++i) acc[i] = 0.0f;
                acc = __builtin_amdgcn_mfma_f32_32x32x16_bf16(a[gi][0], b0, acc, 0, 0, 0);
                acc = __builtin_amdgcn_mfma_f32_32x32x16_bf16(a[gi][1], b1, acc, 0, 0, 0);
                acc = __builtin_amdgcn_mfma_f32_32x32x16_bf16(a[gi][2], b2, acc, 0, 0, 0);
                acc = __builtin_amdgcn_mfma_f32_32x32x16_bf16(a[gi][3], b3, acc, 0, 0, 0);
                #pragma unroll
                for (int r = 0; r < 16; ++r)
                    sums[gi][r] += EXP2F(acc[r] - lse[gi][r]);
            }
        }
    }

    // reduce over the 32 lanes (cols) of each half-wave
    #pragma unroll
    for (int gi = 0; gi < 2; ++gi)
        #pragma unroll
        for (int r = 0; r < 16; ++r) {
            float s = sums[gi][r];
            s += __shfl_xor(s, 1);
            s += __shfl_xor(s, 2);
            s += __shfl_xor(s, 4);
            s += __shfl_xor(s, 8);
            s += __shfl_xor(s, 16);
            sums[gi][r] = s;
        }

    // cross-wave combine (each wave covered a different col span)
    if (mcol == 0) {
        #pragma unroll
        for (int gi = 0; gi < 2; ++gi)
            #pragma unroll
            for (int r = 0; r < 16; ++r) {
                int rl = (r & 3) + 8 * (r >> 2) + 4 * half;
                partials[wave][gi * 32 + rl] = sums[gi][r];
            }
    }
    __syncthreads();

    #pragma unroll
    for (int gi = 0; gi < 2; ++gi)
        #pragma unroll
        for (int r = 0; r < 16; ++r) {
            int rl = gi * 32 + (r & 3) + 8 * (r >> 2) + 4 * half;
            float tot = partials[0][rl] + partials[1][rl] +
                        partials[2][rl] + partials[3][rl] +
                        partials[4][rl] + partials[5][rl] +
                        partials[6][rl] + partials[7][rl];
            lse[gi][r] += __log2f(tot);   // lse2 = m2 + log2(sum exp2(s2-m2))
        }

    // ---------------- pass 2: recompute + write ----------------
    float* outb = Out + (size_t)b * N_ * N_;
    {
        const bf16_t* bp0 = Pb + (size_t)wave * 2048 + (size_t)lane * 8;
        bf16x8 nb0 = *(const bf16x8*)(bp0);
        bf16x8 nb1 = *(const bf16x8*)(bp0 + 512);
        bf16x8 nb2 = *(const bf16x8*)(bp0 + 1024);
        bf16x8 nb3 = *(const bf16x8*)(bp0 + 1536);
        for (int t = 0; t < N_ / 256; ++t) {
            const int c0 = (t * 8 + wave) * 32;
            bf16x8 b0 = nb0, b1 = nb1, b2 = nb2, b3 = nb3;
            if (t + 1 < N_ / 256) {
                const bf16_t* np = Pb + (size_t)((t + 1) * 8 + wave) * 2048
                                      + (size_t)lane * 8;
                nb0 = *(const bf16x8*)(np);
                nb1 = *(const bf16x8*)(np + 512);
                nb2 = *(const bf16x8*)(np + 1024);
                nb3 = *(const bf16x8*)(np + 1536);
            }
            #pragma unroll
            for (int gi = 0; gi < 2; ++gi) {
                f32x16 acc;
                #pragma unroll
                for (int i = 0; i < 16; ++i) acc[i] = 0.0f;
                acc = __builtin_amdgcn_mfma_f32_32x32x16_bf16(a[gi][0], b0, acc, 0, 0, 0);
                acc = __builtin_amdgcn_mfma_f32_32x32x16_bf16(a[gi][1], b1, acc, 0, 0, 0);
                acc = __builtin_amdgcn_mfma_f32_32x32x16_bf16(a[gi][2], b2, acc, 0, 0, 0);
                acc = __builtin_amdgcn_mfma_f32_32x32x16_bf16(a[gi][3], b3, acc, 0, 0, 0);
                #pragma unroll
                for (int r = 0; r < 16; ++r) {
                    int row = rowbase + gi * 32 +
                              (r & 3) + 8 * (r >> 2) + 4 * half;
                    outb[(size_t)row * N_ + (c0 + mcol)] =
                        EXP2F(acc[r] - lse[gi][r]);
                }
            }
        }
    }
}

extern "C" void kernel_launch(void* const* d_in, const int* in_sizes, int n_in,
                              void* d_out, int out_size, void* d_ws, size_t ws_size,
                              hipStream_t stream) {
    const float* X = (const float*)d_in[0];
    float* Out     = (float*)d_out;

    bf16_t* Xp    = (bf16_t*)d_ws;                                   // 2 MB packed
    float*  norms = (float*)((char*)d_ws + (size_t)B_ * N_ * D_ * sizeof(bf16_t)); // 64 KB

    conv_pack_kernel<<<(B_ * N_) / 128, 256, 0, stream>>>(X, Xp, norms);
    softmax_xxt_kernel<<<(B_ * N_) / 64, 512, 0, stream>>>(Xp, norms, Out);
}